// Round 1
// baseline (11643.746 us; speedup 1.0000x reference)
//
#include <hip/hip_runtime.h>
#include <stdint.h>

#define BB 512
#define TT 256
#define HH 512
#define G3 1536
#define NVOC 30

#define GROUPS 32
#define BT 16      // batch rows per group
#define JBL 8      // j-blocks per group
#define JT 64      // hidden cols per j-block
#define NBLK 256   // GROUPS*JBL

typedef float f32x4 __attribute__((ext_vector_type(4)));
typedef short s16x8 __attribute__((ext_vector_type(8)));

__device__ __forceinline__ unsigned short f2bf(float f) {
    unsigned u = __float_as_uint(f);
    u = u + 0x7FFFu + ((u >> 16) & 1u);   // RNE
    return (unsigned short)(u >> 16);
}
__device__ __forceinline__ float bf2f(unsigned short s) {
    return __uint_as_float(((unsigned)s) << 16);
}
__device__ __forceinline__ float sigm(float x) { return 1.f / (1.f + __expf(-x)); }
__device__ __forceinline__ float tanh_fast(float x) {
    x = fminf(15.f, fmaxf(-15.f, x));
    float e = __expf(2.f * x);
    return (e - 1.f) / (e + 1.f);
}

__global__ void k_wconv(const float* __restrict__ w, unsigned short* __restrict__ wbf, int n) {
    int i = blockIdx.x * blockDim.x + threadIdx.x;
    if (i < n) wbf[i] = f2bf(w[i]);
}

// gi_table[v][g] = embed[v] . w_ih[g] + b_ih[g] + (g<1024 ? b_hh[g] : 0)
__global__ void k_gitab(const float* __restrict__ embed, const float* __restrict__ w_ih,
                        const float* __restrict__ b_ih, const float* __restrict__ b_hh,
                        float* __restrict__ gi) {
    int id = blockIdx.x * blockDim.x + threadIdx.x;
    if (id >= NVOC * G3) return;
    int v = id / G3, g = id - v * G3;
    float s = b_ih[g] + (g < 2 * HH ? b_hh[g] : 0.f);
    const float* er = embed + (size_t)v * HH;   // EMBED == HH == 512
    const float* wr = w_ih + (size_t)g * HH;
    #pragma unroll 8
    for (int k = 0; k < HH; ++k) s += er[k] * wr[k];
    gi[id] = s;
}

// h0 = embed[x[:,0]] split into bf16 hi/lo; lastvalid[b] = (first t>=1 with x==0) - 1, else 255
__global__ void k_init(const int* __restrict__ x32, const float* __restrict__ embed,
                       unsigned short* __restrict__ hh0, unsigned short* __restrict__ hl0,
                       int* __restrict__ lastvalid) {
    int b = blockIdx.x, lane = threadIdx.x;
    int is64 = (x32[1] == 0) ? 1 : 0;   // int64 inputs read as int32 pairs (LE)
    int xv0 = x32[(b * TT) << is64];
    for (int k = lane; k < HH; k += 64) {
        float e = embed[(size_t)xv0 * HH + k];
        unsigned short hi = f2bf(e);
        unsigned short lo = f2bf(e - bf2f(hi));
        hh0[(size_t)b * HH + k] = hi;
        hl0[(size_t)b * HH + k] = lo;
    }
    int m = TT;
    for (int t = 1 + lane; t < TT; t += 64)
        if (x32[(b * TT + t) << is64] == 0) m = min(m, t);
    #pragma unroll
    for (int off = 32; off; off >>= 1) m = min(m, __shfl_xor(m, off));
    if (lane == 0) lastvalid[b] = m - 1;
}

// Persistent per-step GRU. 256 blocks x 256 threads (4 waves), 1 block/CU (LDS pad).
// block -> (group, jb): group's 8 blocks land on the same XCD under round-robin (perf only).
__global__ void __launch_bounds__(256, 1)
k_main(const int* __restrict__ x32, const unsigned short* __restrict__ wbf,
       const float* __restrict__ gi_table, const float* __restrict__ b_hh,
       unsigned short* __restrict__ hh, unsigned short* __restrict__ hl,
       const int* __restrict__ lastvalid, int* __restrict__ flags) {
    __shared__ char lds_pad[98304];            // force 1 block/CU -> all 256 blocks resident
    if (threadIdx.x == 0) ((volatile char*)lds_pad)[0] = 0;

    int blk = blockIdx.x;
    int xcd = blk & 7, s = blk >> 3;
    int group = xcd * 4 + (s >> 3);            // 0..31
    int jb = s & 7;                            // 0..7
    int b0 = group * BT;
    int wave = threadIdx.x >> 6, lane = threadIdx.x & 63;
    int l16 = lane & 15, lq = lane >> 4;
    int j0 = jb * JT + wave * 16;
    int jc = j0 + l16;                         // this lane's hidden column (B col / D col)
    int kbase = lq * 8;
    int is64 = (x32[1] == 0) ? 1 : 0;

    // persistent weight fragments: B[k][n] = w_hh[gate*512 + n][k], n = jc
    s16x8 wreg[3][16];
    #pragma unroll
    for (int g = 0; g < 3; ++g)
        #pragma unroll
        for (int c = 0; c < 16; ++c)
            wreg[g][c] = *reinterpret_cast<const s16x8*>(
                wbf + (size_t)(g * HH + jc) * HH + c * 32 + kbase);

    float bhn = b_hh[2 * HH + jc];
    int lv[4];
    #pragma unroll
    for (int i = 0; i < 4; ++i) lv[i] = lastvalid[b0 + lq * 4 + i];
    int gmax = 0;
    for (int r = 0; r < BT; ++r) gmax = max(gmax, lastvalid[b0 + r]);

    int* myflag = flags + group * JBL + jb;
    const int fbase = group * JBL;

    for (int t = 1; t <= gmax; ++t) {
        // wait until all 8 producers of this group published step t-1
        int want = t - 1;
        int guard = 0;
        for (;;) {
            int f = 0x7fffffff;
            if (lane < JBL)
                f = __hip_atomic_load(flags + fbase + lane, __ATOMIC_RELAXED,
                                      __HIP_MEMORY_SCOPE_AGENT);
            if (__all(f >= want)) break;
            __builtin_amdgcn_s_sleep(1);
            if (++guard > (1 << 26)) break;    // safety: no infinite hang
        }
        __threadfence();                       // acquire: invalidate stale cache

        const unsigned short* hhr = hh + (size_t)((t - 1) & 1) * BB * HH;
        const unsigned short* hlr = hl + (size_t)((t - 1) & 1) * BB * HH;
        unsigned short* hhw = hh + (size_t)(t & 1) * BB * HH;
        unsigned short* hlw = hl + (size_t)(t & 1) * BB * HH;

        // epilogue operands issued early so MFMAs hide their latency
        int xv[4]; float hp[4];
        #pragma unroll
        for (int i = 0; i < 4; ++i) {
            int row = b0 + lq * 4 + i;
            xv[i] = x32[((row * TT) + t) << is64];
            hp[i] = bf2f(hhr[(size_t)row * HH + jc]) + bf2f(hlr[(size_t)row * HH + jc]);
        }
        float gr[4], gz[4], gn[4];
        #pragma unroll
        for (int i = 0; i < 4; ++i) {
            const float* gt = gi_table + (size_t)xv[i] * G3;
            gr[i] = gt[jc]; gz[i] = gt[HH + jc]; gn[i] = gt[2 * HH + jc];
        }

        f32x4 acc0 = {0.f, 0.f, 0.f, 0.f}, acc1 = acc0, acc2 = acc0;
        const unsigned short* arow_hi = hhr + (size_t)(b0 + l16) * HH + kbase;
        const unsigned short* arow_lo = hlr + (size_t)(b0 + l16) * HH + kbase;
        #pragma unroll
        for (int c = 0; c < 16; ++c) {
            s16x8 ahi = *reinterpret_cast<const s16x8*>(arow_hi + c * 32);
            s16x8 alo = *reinterpret_cast<const s16x8*>(arow_lo + c * 32);
            acc0 = __builtin_amdgcn_mfma_f32_16x16x32_bf16(ahi, wreg[0][c], acc0, 0, 0, 0);
            acc1 = __builtin_amdgcn_mfma_f32_16x16x32_bf16(ahi, wreg[1][c], acc1, 0, 0, 0);
            acc2 = __builtin_amdgcn_mfma_f32_16x16x32_bf16(ahi, wreg[2][c], acc2, 0, 0, 0);
            acc0 = __builtin_amdgcn_mfma_f32_16x16x32_bf16(alo, wreg[0][c], acc0, 0, 0, 0);
            acc1 = __builtin_amdgcn_mfma_f32_16x16x32_bf16(alo, wreg[1][c], acc1, 0, 0, 0);
            acc2 = __builtin_amdgcn_mfma_f32_16x16x32_bf16(alo, wreg[2][c], acc2, 0, 0, 0);
        }

        // D layout (m89-verified): col = lane&15, row = (lane>>4)*4 + i
        #pragma unroll
        for (int i = 0; i < 4; ++i) {
            int row = b0 + lq * 4 + i;
            float r = sigm(acc0[i] + gr[i]);
            float z = sigm(acc1[i] + gz[i]);
            float n = tanh_fast(gn[i] + r * (acc2[i] + bhn));
            float hnew = (1.f - z) * n + z * hp[i];
            float hout = (t <= lv[i]) ? hnew : hp[i];
            unsigned short hi = f2bf(hout);
            unsigned short lo = f2bf(hout - bf2f(hi));
            hhw[(size_t)row * HH + jc] = hi;
            hlw[(size_t)row * HH + jc] = lo;
        }

        __threadfence();                       // release: drain + write back before flag
        __syncthreads();
        if (threadIdx.x == 0)
            __hip_atomic_store(myflag, t, __ATOMIC_RELAXED, __HIP_MEMORY_SCOPE_AGENT);
    }
}

__global__ void k_logits(const unsigned short* __restrict__ hh, const unsigned short* __restrict__ hl,
                         const int* __restrict__ lastvalid, const float* __restrict__ fc_w,
                         const float* __restrict__ fc_b, float* __restrict__ out) {
    int wave = threadIdx.x >> 6, lane = threadIdx.x & 63;
    int row = blockIdx.x * 4 + wave;
    if (row >= BB) return;
    int g0 = (row / BT) * BT;
    int gmax = 0;
    for (int r = 0; r < BT; ++r) gmax = max(gmax, lastvalid[g0 + r]);
    const unsigned short* hhf = hh + (size_t)(gmax & 1) * BB * HH + (size_t)row * HH;
    const unsigned short* hlf = hl + (size_t)(gmax & 1) * BB * HH + (size_t)row * HH;
    float d0 = 0.f, d1 = 0.f;
    int k = lane * 8;                          // 64 lanes x 8 = 512, single pass
    #pragma unroll
    for (int u = 0; u < 8; ++u) {
        float hv = bf2f(hhf[k + u]) + bf2f(hlf[k + u]);
        d0 += hv * fc_w[k + u];
        d1 += hv * fc_w[HH + k + u];
    }
    #pragma unroll
    for (int off = 32; off; off >>= 1) {
        d0 += __shfl_xor(d0, off);
        d1 += __shfl_xor(d1, off);
    }
    if (lane == 0) {
        out[row * 2 + 0] = d0 + fc_b[0];
        out[row * 2 + 1] = d1 + fc_b[1];
    }
}

extern "C" void kernel_launch(void* const* d_in, const int* in_sizes, int n_in,
                              void* d_out, int out_size, void* d_ws, size_t ws_size,
                              hipStream_t stream) {
    const int*   x32   = (const int*)d_in[0];
    const float* embed = (const float*)d_in[1];
    const float* w_ih  = (const float*)d_in[2];
    const float* w_hh  = (const float*)d_in[3];
    const float* b_ih  = (const float*)d_in[4];
    const float* b_hh  = (const float*)d_in[5];
    const float* fc_w  = (const float*)d_in[6];
    const float* fc_b  = (const float*)d_in[7];
    float* out = (float*)d_out;

    char* ws = (char*)d_ws;
    unsigned short* wbf = (unsigned short*)ws;               // 1536*512*2 = 1572864 B
    unsigned short* hh  = (unsigned short*)(ws + 1572864);   // 2 bufs * 512*512*2 = 1048576 B
    unsigned short* hl  = (unsigned short*)(ws + 2621440);   // 1048576 B
    float* gi_table     = (float*)(ws + 3670016);            // 30*1536*4 = 184320 B
    int* lastvalid      = (int*)(ws + 3854336);              // 2048 B
    int* flags          = (int*)(ws + 3856384);              // 1024 B

    hipMemsetAsync(flags, 0, NBLK * sizeof(int), stream);
    k_wconv<<<(G3 * HH + 255) / 256, 256, 0, stream>>>(w_hh, wbf, G3 * HH);
    k_gitab<<<(NVOC * G3 + 255) / 256, 256, 0, stream>>>(embed, w_ih, b_ih, b_hh, gi_table);
    k_init<<<BB, 64, 0, stream>>>(x32, embed, hh, hl, lastvalid);
    k_main<<<NBLK, 256, 0, stream>>>(x32, wbf, gi_table, b_hh, hh, hl, lastvalid, flags);
    k_logits<<<BB / 4, 256, 0, stream>>>(hh, hl, lastvalid, fc_w, fc_b, out);
}

// Round 3
// 1739.624 us; speedup vs baseline: 6.6933x; 6.6933x over previous
//
#include <hip/hip_runtime.h>
#include <stdint.h>

#define BB 512
#define TT 256
#define HH 512
#define G3 1536
#define NVOC 30

#define GROUPS 32
#define BT 16      // batch rows per group
#define JBL 8      // j-blocks per group
#define JT 64      // hidden cols per j-block
#define NBLK 256   // GROUPS*JBL

typedef float f32x4 __attribute__((ext_vector_type(4)));
typedef short s16x8 __attribute__((ext_vector_type(8)));
typedef unsigned int u32;
typedef unsigned long long u64;

__device__ __forceinline__ unsigned short f2bf(float f) {
    unsigned u = __float_as_uint(f);
    u = u + 0x7FFFu + ((u >> 16) & 1u);   // RNE
    return (unsigned short)(u >> 16);
}
__device__ __forceinline__ float bf2f(unsigned short s) {
    return __uint_as_float(((unsigned)s) << 16);
}
__device__ __forceinline__ float sigm(float x) { return 1.f / (1.f + __expf(-x)); }
__device__ __forceinline__ float tanh_fast(float x) {
    x = fminf(15.f, fmaxf(-15.f, x));
    float e = __expf(2.f * x);
    return (e - 1.f) / (e + 1.f);
}

__global__ void k_wconv(const float* __restrict__ w, unsigned short* __restrict__ wbf, int n) {
    int i = blockIdx.x * blockDim.x + threadIdx.x;
    if (i < n) wbf[i] = f2bf(w[i]);
}

// gi_table[v][g] = embed[v] . w_ih[g] + b_ih[g] + (g<1024 ? b_hh[g] : 0)
__global__ void k_gitab(const float* __restrict__ embed, const float* __restrict__ w_ih,
                        const float* __restrict__ b_ih, const float* __restrict__ b_hh,
                        float* __restrict__ gi) {
    int id = blockIdx.x * blockDim.x + threadIdx.x;
    if (id >= NVOC * G3) return;
    int v = id / G3, g = id - v * G3;
    float s = b_ih[g] + (g < 2 * HH ? b_hh[g] : 0.f);
    const float* er = embed + (size_t)v * HH;   // EMBED == HH == 512
    const float* wr = w_ih + (size_t)g * HH;
    #pragma unroll 8
    for (int k = 0; k < HH; ++k) s += er[k] * wr[k];
    gi[id] = s;
}

// h0 = embed[x[:,0]] packed (hi<<16 | lo); lastvalid[b] = last valid step index
__global__ void k_init(const int* __restrict__ x32, const float* __restrict__ embed,
                       u32* __restrict__ h_pk, int* __restrict__ lastvalid) {
    int b = blockIdx.x, lane = threadIdx.x;
    int is64 = (x32[1] == 0) ? 1 : 0;   // int64 inputs read as int32 pairs (LE)
    int xv0 = x32[(b * TT) << is64];
    for (int k = lane; k < HH; k += 64) {
        float e = embed[(size_t)xv0 * HH + k];
        unsigned short hi = f2bf(e);
        unsigned short lo = f2bf(e - bf2f(hi));
        h_pk[(size_t)b * HH + k] = ((u32)hi << 16) | (u32)lo;
    }
    int m = TT;
    for (int t = 1 + lane; t < TT; t += 64)
        if (x32[(b * TT + t) << is64] == 0) m = min(m, t);
    #pragma unroll
    for (int off = 32; off; off >>= 1) m = min(m, __shfl_xor(m, off));
    if (lane == 0) lastvalid[b] = m - 1;
}

// Persistent per-step GRU. 256 blocks x 256 threads, 1 block/CU (LDS pad).
// NO fences: all cross-block traffic via agent-scope relaxed atomics (coherent
// at device level regardless of XCD placement); ordering via vmcnt(0)+barrier.
__global__ void __launch_bounds__(256, 1)
k_main(const int* __restrict__ x32, const unsigned short* __restrict__ wbf,
       const float* __restrict__ gi_table, const float* __restrict__ b_hh,
       u32* __restrict__ h_pk, const int* __restrict__ lastvalid, int* __restrict__ flags) {
    __shared__ unsigned short h_hi[BT * HH];   // 16 KB, bank-swizzled
    __shared__ unsigned short h_lo[BT * HH];   // 16 KB
    __shared__ char lds_pad[56 * 1024];        // total 88KB -> 1 block/CU
    if (threadIdx.x == 0) ((volatile char*)lds_pad)[0] = 0;

    const int blk = blockIdx.x;
    const int xcd = blk & 7, s = blk >> 3;
    const int group = xcd * 4 + (s >> 3);      // 0..31 (8 blocks/group; same-XCD under RR, perf only)
    const int jb = s & 7;                      // 0..7
    const int b0 = group * BT;
    const int tid = threadIdx.x;
    const int wave = tid >> 6, lane = tid & 63;
    const int l16 = lane & 15, lq = lane >> 4;
    const int jc = jb * JT + wave * 16 + l16;  // this lane's hidden column
    const int kb16 = lq * 8;                   // element offset within 32-wide k-chunk
    const int is64 = (x32[1] == 0) ? 1 : 0;

    // persistent weight fragments: B[k][n] = w_hh[gate*512 + n][k], n = jc
    s16x8 wreg[3][16];
    #pragma unroll
    for (int g = 0; g < 3; ++g)
        #pragma unroll
        for (int c = 0; c < 16; ++c)
            wreg[g][c] = *reinterpret_cast<const s16x8*>(
                wbf + (size_t)(g * HH + jc) * HH + c * 32 + kb16);
    // PIN: round-1 counters showed VGPR_Count=136 < 192 needed -> compiler had
    // sunk these loads into the t-loop (re-fetching 48KB/block/step from L2).
    // The empty asm makes each fragment opaque: it must stay register-resident.
    #pragma unroll
    for (int g = 0; g < 3; ++g)
        #pragma unroll
        for (int c = 0; c < 16; ++c)
            asm volatile("" : "+v"(wreg[g][c]));

    float bhn = b_hh[2 * HH + jc];
    asm volatile("" : "+v"(bhn));
    int lv[4]; float hp[4];
    #pragma unroll
    for (int i = 0; i < 4; ++i) {
        int row = b0 + lq * 4 + i;
        lv[i] = lastvalid[row];
        asm volatile("" : "+v"(lv[i]));
        u32 p = h_pk[(size_t)row * HH + jc];   // written by k_init (kernel boundary => coherent)
        hp[i] = bf2f((unsigned short)(p >> 16)) + bf2f((unsigned short)(p & 0xffffu));
    }
    int gmax = 0;
    for (int r = 0; r < BT; ++r) gmax = max(gmax, lastvalid[b0 + r]);

    int* myflag = flags + group * JBL + jb;
    int* fbase = flags + group * JBL;
    u32* hbuf0 = h_pk;
    u32* hbuf1 = h_pk + (size_t)BB * HH;

    for (int t = 1; t <= gmax; ++t) {
        // constant-side loads first: overlap with the flag wait
        int xv[4]; float gr[4], gz[4], gn[4];
        #pragma unroll
        for (int i = 0; i < 4; ++i) {
            int row = b0 + lq * 4 + i;
            xv[i] = x32[((row * TT) + t) << is64];
        }
        #pragma unroll
        for (int i = 0; i < 4; ++i) {
            const float* gt = gi_table + (size_t)xv[i] * G3;
            gr[i] = gt[jc]; gz[i] = gt[HH + jc]; gn[i] = gt[2 * HH + jc];
        }

        // wait until all 8 producers of this group published step t-1
        {
            const int want = t - 1;
            int guard = 0;
            for (;;) {
                int f = 0x7fffffff;
                if (lane < JBL)
                    f = __hip_atomic_load(fbase + lane, __ATOMIC_RELAXED,
                                          __HIP_MEMORY_SCOPE_AGENT);
                if (__all(f >= want)) break;
                __builtin_amdgcn_s_sleep(1);
                if (++guard > (1 << 17)) break;    // bounded: ~26ms/step worst case
            }
        }
        asm volatile("" ::: "memory");             // no hoisting of data loads above poll

        // stage group's h slice into LDS (coherent u64 loads), split hi/lo planes,
        // XOR-swizzle by (row&7) so fragment ds_read_b128 is bank-uniform
        {
            const u32* rd = ((t - 1) & 1) ? hbuf1 : hbuf0;
            const u64* src = reinterpret_cast<const u64*>(rd + (size_t)b0 * HH);
            u32* hi32 = reinterpret_cast<u32*>(h_hi);
            u32* lo32 = reinterpret_cast<u32*>(h_lo);
            #pragma unroll
            for (int u = 0; u < 16; ++u) {
                u64 v = __hip_atomic_load(const_cast<u64*>(src) + (size_t)u * 256 + tid,
                                          __ATOMIC_RELAXED, __HIP_MEMORY_SCOPE_AGENT);
                u32 p0 = (u32)v, p1 = (u32)(v >> 32);          // elements k=2tid, 2tid+1
                int idx = (u * 256 + tid) ^ ((u & 7) << 2);    // u32-unit index, swizzled
                hi32[idx] = (p1 & 0xffff0000u) | (p0 >> 16);
                lo32[idx] = (p1 << 16) | (p0 & 0xffffu);
            }
        }
        __syncthreads();

        f32x4 acc0 = {0.f,0.f,0.f,0.f}, acc1 = acc0, acc2 = acc0;
        const int swz = (l16 & 7) << 3;            // u16-unit swizzle
        const int rbase = l16 * HH + kb16;
        #pragma unroll
        for (int c = 0; c < 16; ++c) {
            int idx = (rbase + c * 32) ^ swz;
            s16x8 ahi = *reinterpret_cast<const s16x8*>(h_hi + idx);
            s16x8 alo = *reinterpret_cast<const s16x8*>(h_lo + idx);
            acc0 = __builtin_amdgcn_mfma_f32_16x16x32_bf16(ahi, wreg[0][c], acc0, 0, 0, 0);
            acc1 = __builtin_amdgcn_mfma_f32_16x16x32_bf16(ahi, wreg[1][c], acc1, 0, 0, 0);
            acc2 = __builtin_amdgcn_mfma_f32_16x16x32_bf16(ahi, wreg[2][c], acc2, 0, 0, 0);
            acc0 = __builtin_amdgcn_mfma_f32_16x16x32_bf16(alo, wreg[0][c], acc0, 0, 0, 0);
            acc1 = __builtin_amdgcn_mfma_f32_16x16x32_bf16(alo, wreg[1][c], acc1, 0, 0, 0);
            acc2 = __builtin_amdgcn_mfma_f32_16x16x32_bf16(alo, wreg[2][c], acc2, 0, 0, 0);
        }

        // D layout (m89-verified): col = lane&15, row = (lane>>4)*4 + i
        u32* dst = (t & 1) ? hbuf1 : hbuf0;
        #pragma unroll
        for (int i = 0; i < 4; ++i) {
            int row = b0 + lq * 4 + i;
            float r = sigm(acc0[i] + gr[i]);
            float z = sigm(acc1[i] + gz[i]);
            float n = tanh_fast(gn[i] + r * (acc2[i] + bhn));
            float hnew = (1.f - z) * n + z * hp[i];
            float hout = (t <= lv[i]) ? hnew : hp[i];
            hp[i] = hout;                           // own h carried in registers
            unsigned short hi = f2bf(hout);
            unsigned short lo = f2bf(hout - bf2f(hi));
            __hip_atomic_store(dst + (size_t)row * HH + jc,
                               ((u32)hi << 16) | (u32)lo,
                               __ATOMIC_RELAXED, __HIP_MEMORY_SCOPE_AGENT);
        }
        asm volatile("s_waitcnt vmcnt(0)" ::: "memory");  // h stores at coherence point
        __syncthreads();                                   // all waves done (also guards LDS reuse)
        if (tid == 0)
            __hip_atomic_store(myflag, t, __ATOMIC_RELAXED, __HIP_MEMORY_SCOPE_AGENT);
    }
}

__global__ void k_logits(const u32* __restrict__ h_pk, const int* __restrict__ lastvalid,
                         const float* __restrict__ fc_w, const float* __restrict__ fc_b,
                         float* __restrict__ out) {
    int wave = threadIdx.x >> 6, lane = threadIdx.x & 63;
    int row = blockIdx.x * 4 + wave;
    if (row >= BB) return;
    int g0 = (row / BT) * BT;
    int gmax = 0;
    for (int r = 0; r < BT; ++r) gmax = max(gmax, lastvalid[g0 + r]);
    const u32* hf = h_pk + (size_t)(gmax & 1) * BB * HH + (size_t)row * HH;
    float d0 = 0.f, d1 = 0.f;
    int k = lane * 8;                          // 64 lanes x 8 = 512, single pass
    #pragma unroll
    for (int u = 0; u < 8; ++u) {
        u32 p = hf[k + u];
        float hv = bf2f((unsigned short)(p >> 16)) + bf2f((unsigned short)(p & 0xffffu));
        d0 += hv * fc_w[k + u];
        d1 += hv * fc_w[HH + k + u];
    }
    #pragma unroll
    for (int off = 32; off; off >>= 1) {
        d0 += __shfl_xor(d0, off);
        d1 += __shfl_xor(d1, off);
    }
    if (lane == 0) {
        out[row * 2 + 0] = d0 + fc_b[0];
        out[row * 2 + 1] = d1 + fc_b[1];
    }
}

extern "C" void kernel_launch(void* const* d_in, const int* in_sizes, int n_in,
                              void* d_out, int out_size, void* d_ws, size_t ws_size,
                              hipStream_t stream) {
    const int*   x32   = (const int*)d_in[0];
    const float* embed = (const float*)d_in[1];
    const float* w_ih  = (const float*)d_in[2];
    const float* w_hh  = (const float*)d_in[3];
    const float* b_ih  = (const float*)d_in[4];
    const float* b_hh  = (const float*)d_in[5];
    const float* fc_w  = (const float*)d_in[6];
    const float* fc_b  = (const float*)d_in[7];
    float* out = (float*)d_out;

    char* ws = (char*)d_ws;
    unsigned short* wbf = (unsigned short*)ws;               // 1536*512*2 = 1572864 B
    u32* h_pk           = (u32*)(ws + 1572864);              // 2 bufs * 512*512*4 = 2097152 B
    float* gi_table     = (float*)(ws + 3670016);            // 30*1536*4 = 184320 B
    int* lastvalid      = (int*)(ws + 3854336);              // 2048 B
    int* flags          = (int*)(ws + 3856384);              // 1024 B

    hipMemsetAsync(flags, 0, NBLK * sizeof(int), stream);
    k_wconv<<<(G3 * HH + 255) / 256, 256, 0, stream>>>(w_hh, wbf, G3 * HH);
    k_gitab<<<(NVOC * G3 + 255) / 256, 256, 0, stream>>>(embed, w_ih, b_ih, b_hh, gi_table);
    k_init<<<BB, 64, 0, stream>>>(x32, embed, h_pk, lastvalid);
    k_main<<<NBLK, 256, 0, stream>>>(x32, wbf, gi_table, b_hh, h_pk, lastvalid, flags);
    k_logits<<<BB / 4, 256, 0, stream>>>(h_pk, lastvalid, fc_w, fc_b, out);
}

// Round 4
// 1318.558 us; speedup vs baseline: 8.8307x; 1.3193x over previous
//
#include <hip/hip_runtime.h>
#include <stdint.h>

#define BB 512
#define TT 256
#define HH 512
#define G3 1536
#define NVOC 30

#define GROUPS 32
#define BT 16      // batch rows per group
#define JBL 8      // j-blocks per group
#define JT 64      // hidden cols per j-block
#define NBLK 256   // GROUPS*JBL

typedef float f32x4 __attribute__((ext_vector_type(4)));
typedef short s16x8 __attribute__((ext_vector_type(8)));
typedef unsigned int u32;
typedef unsigned long long u64;

__device__ __forceinline__ unsigned short f2bf(float f) {
    unsigned u = __float_as_uint(f);
    u = u + 0x7FFFu + ((u >> 16) & 1u);   // RNE
    return (unsigned short)(u >> 16);
}
__device__ __forceinline__ float bf2f(unsigned short s) {
    return __uint_as_float(((unsigned)s) << 16);
}
__device__ __forceinline__ float sigm(float x) { return 1.f / (1.f + __expf(-x)); }
__device__ __forceinline__ float tanh_fast(float x) {
    x = fminf(15.f, fmaxf(-15.f, x));
    float e = __expf(2.f * x);
    return (e - 1.f) / (e + 1.f);
}

__global__ void k_wconv(const float* __restrict__ w, unsigned short* __restrict__ wbf, int n) {
    int i = blockIdx.x * blockDim.x + threadIdx.x;
    if (i < n) wbf[i] = f2bf(w[i]);
}

// gi_table[v][g] = embed[v] . w_ih[g] + b_ih[g] + (g<1024 ? b_hh[g] : 0)
__global__ void k_gitab(const float* __restrict__ embed, const float* __restrict__ w_ih,
                        const float* __restrict__ b_ih, const float* __restrict__ b_hh,
                        float* __restrict__ gi) {
    int id = blockIdx.x * blockDim.x + threadIdx.x;
    if (id >= NVOC * G3) return;
    int v = id / G3, g = id - v * G3;
    float s = b_ih[g] + (g < 2 * HH ? b_hh[g] : 0.f);
    const float* er = embed + (size_t)v * HH;   // EMBED == HH == 512
    const float* wr = w_ih + (size_t)g * HH;
    #pragma unroll 8
    for (int k = 0; k < HH; ++k) s += er[k] * wr[k];
    gi[id] = s;
}

// h0 -> slot0 with tag 0; slot1 scrubbed with tag 2 (kills replay ghosts at t=2).
// Packed h u32 = (bf16_hi << 16) | (bf16_lo & 0xFFFC) | tag2bits.
__global__ void k_init(const int* __restrict__ x32, const float* __restrict__ embed,
                       u32* __restrict__ h_pk, int* __restrict__ lastvalid) {
    int b = blockIdx.x, lane = threadIdx.x;
    int is64 = (x32[1] == 0) ? 1 : 0;   // int64 inputs read as int32 pairs (LE)
    int xv0 = x32[(b * TT) << is64];
    for (int k = lane; k < HH; k += 64) {
        float e = embed[(size_t)xv0 * HH + k];
        unsigned short hi = f2bf(e);
        unsigned short lo = f2bf(e - bf2f(hi));
        u32 pk = ((u32)hi << 16) | (u32)(lo & 0xFFFC);
        h_pk[(size_t)b * HH + k] = pk;                      // slot 0, tag 0
        h_pk[(size_t)BB * HH + (size_t)b * HH + k] = pk | 2u; // slot 1 scrub, tag 2
    }
    int m = TT;
    for (int t = 1 + lane; t < TT; t += 64)
        if (x32[(b * TT + t) << is64] == 0) m = min(m, t);
    #pragma unroll
    for (int off = 32; off; off >>= 1) m = min(m, __shfl_xor(m, off));
    if (lane == 0) lastvalid[b] = m - 1;
}

// Persistent per-step GRU. 256 blocks x 256 threads, 1 block/CU (LDS pad).
// Cross-block h via agent-scope relaxed atomics with 2-bit step tags in the
// data itself (consumer polls tags, NOT flags). Flags only give lagged
// back-pressure + store-visibility certification, off the critical path.
__global__ void __launch_bounds__(256, 1)
k_main(const int* __restrict__ x32, const unsigned short* __restrict__ wbf,
       const float* __restrict__ gi_table, const float* __restrict__ b_hh,
       u32* __restrict__ h_pk, const int* __restrict__ lastvalid, int* __restrict__ flags) {
    __shared__ unsigned short h_hi[BT * HH];   // 16 KB
    __shared__ unsigned short h_lo[BT * HH];   // 16 KB
    __shared__ char lds_pad[56 * 1024];        // total 88KB -> 1 block/CU
    if (threadIdx.x == 0) ((volatile char*)lds_pad)[0] = 0;

    const int blk = blockIdx.x;
    const int xcd = blk & 7, s = blk >> 3;
    const int group = xcd * 4 + (s >> 3);      // 0..31
    const int jb = s & 7;                      // 0..7
    const int b0 = group * BT;
    const int tid = threadIdx.x;
    const int wave = tid >> 6, lane = tid & 63;
    const int l16 = lane & 15, lq = lane >> 4;
    const int jc = jb * JT + wave * 16 + l16;  // this lane's hidden column
    const int kb16 = lq * 8;                   // u16 offset within 32-wide k-chunk
    const int is64 = (x32[1] == 0) ? 1 : 0;

    // persistent weight fragments: B[k][n] = w_hh[gate*512 + n][k], n = jc
    s16x8 wreg[3][16];
    #pragma unroll
    for (int g = 0; g < 3; ++g)
        #pragma unroll
        for (int c = 0; c < 16; ++c)
            wreg[g][c] = *reinterpret_cast<const s16x8*>(
                wbf + (size_t)(g * HH + jc) * HH + c * 32 + kb16);
    #pragma unroll
    for (int g = 0; g < 3; ++g)
        #pragma unroll
        for (int c = 0; c < 16; ++c)
            asm volatile("" : "+v"(wreg[g][c]));   // pin: keep register-resident

    float bhn = b_hh[2 * HH + jc];
    asm volatile("" : "+v"(bhn));
    int lv[4]; float hp[4];
    #pragma unroll
    for (int i = 0; i < 4; ++i) {
        int row = b0 + lq * 4 + i;
        lv[i] = lastvalid[row];
        asm volatile("" : "+v"(lv[i]));
        u32 p = h_pk[(size_t)row * HH + jc];
        hp[i] = bf2f((unsigned short)(p >> 16)) + bf2f((unsigned short)(p & 0xFFFC));
    }
    int gmax = 0;
    for (int r = 0; r < BT; ++r) gmax = max(gmax, lastvalid[b0 + r]);

    int* myflag = flags + group * JBL + jb;
    int* fbase = flags + group * JBL;
    u32* hbuf0 = h_pk;
    u32* hbuf1 = h_pk + (size_t)BB * HH;

    for (int t = 1; t <= gmax; ++t) {
        const u32 tg = (u32)((t - 1) & 3);
        const u32 tgpair = tg | (tg << 2);

        // B-issue: first-pass staging loads (16 x u64 per thread = group's 16x512 slice)
        u32* rslot = ((t - 1) & 1) ? hbuf1 : hbuf0;
        u64* src = reinterpret_cast<u64*>(rslot + (size_t)b0 * HH);
        u64 vals[16];
        #pragma unroll
        for (int u = 0; u < 16; ++u)
            vals[u] = __hip_atomic_load(src + (size_t)u * 256 + tid,
                                        __ATOMIC_RELAXED, __HIP_MEMORY_SCOPE_AGENT);

        // A: constant-side loads overlap the staging flight
        int xv[4]; float gr[4], gz[4], gn[4];
        #pragma unroll
        for (int i = 0; i < 4; ++i) {
            int row = b0 + lq * 4 + i;
            xv[i] = x32[((row * TT) + t) << is64];
        }
        #pragma unroll
        for (int i = 0; i < 4; ++i) {
            const float* gt = gi_table + (size_t)xv[i] * G3;
            gr[i] = gt[jc]; gz[i] = gt[HH + jc]; gn[i] = gt[2 * HH + jc];
        }

        // B-check: tag-poll; retry only stale words
        u32 bad = 0;
        #pragma unroll
        for (int u = 0; u < 16; ++u) {
            u32 p0 = (u32)vals[u], p1 = (u32)(vals[u] >> 32);
            u32 tags = (p0 & 3u) | ((p1 & 3u) << 2);
            if (tags != tgpair) bad |= (1u << u);
        }
        int guard = 0;
        while (__any(bad != 0)) {
            #pragma unroll
            for (int u = 0; u < 16; ++u) {
                if (bad & (1u << u)) {
                    u64 v = __hip_atomic_load(src + (size_t)u * 256 + tid,
                                              __ATOMIC_RELAXED, __HIP_MEMORY_SCOPE_AGENT);
                    u32 p0 = (u32)v, p1 = (u32)(v >> 32);
                    if (((p0 & 3u) | ((p1 & 3u) << 2)) == tgpair) {
                        vals[u] = v; bad &= ~(1u << u);
                    }
                }
            }
            if (++guard > (1 << 15)) break;    // safety valve
        }

        // C: unpack into swizzled LDS planes (byte bits [4:7] ^= row[0:3])
        {
            u32* hi32 = reinterpret_cast<u32*>(h_hi);
            u32* lo32 = reinterpret_cast<u32*>(h_lo);
            #pragma unroll
            for (int u = 0; u < 16; ++u) {
                u32 p0 = (u32)vals[u], p1 = (u32)(vals[u] >> 32);
                int idx = u * 256 + (tid ^ ((u & 15) << 2));
                hi32[idx] = (p1 & 0xFFFF0000u) | (p0 >> 16);
                lo32[idx] = (((p1 & 0xFFFFu) << 16) | (p0 & 0xFFFFu)) & 0xFFFCFFFCu;
            }
        }
        __syncthreads();                                   // D: staging complete
        asm volatile("s_waitcnt vmcnt(0)" ::: "memory");   // E: old stores drained (free)
        if (tid == 0)
            __hip_atomic_store(myflag, t, __ATOMIC_RELAXED, __HIP_MEMORY_SCOPE_AGENT);

        // F: MFMA, 6 independent accumulator chains (3 gates x hi/lo)
        f32x4 a0h = {0.f,0.f,0.f,0.f}, a0l = a0h, a1h = a0h, a1l = a0h, a2h = a0h, a2l = a0h;
        const int rowbase = l16 * HH;
        #pragma unroll
        for (int c = 0; c < 16; ++c) {
            int off = rowbase + ((kb16 + c * 32) ^ (l16 << 3));
            s16x8 ahi = *reinterpret_cast<const s16x8*>(h_hi + off);
            s16x8 alo = *reinterpret_cast<const s16x8*>(h_lo + off);
            a0h = __builtin_amdgcn_mfma_f32_16x16x32_bf16(ahi, wreg[0][c], a0h, 0, 0, 0);
            a1h = __builtin_amdgcn_mfma_f32_16x16x32_bf16(ahi, wreg[1][c], a1h, 0, 0, 0);
            a2h = __builtin_amdgcn_mfma_f32_16x16x32_bf16(ahi, wreg[2][c], a2h, 0, 0, 0);
            a0l = __builtin_amdgcn_mfma_f32_16x16x32_bf16(alo, wreg[0][c], a0l, 0, 0, 0);
            a1l = __builtin_amdgcn_mfma_f32_16x16x32_bf16(alo, wreg[1][c], a1l, 0, 0, 0);
            a2l = __builtin_amdgcn_mfma_f32_16x16x32_bf16(alo, wreg[2][c], a2l, 0, 0, 0);
        }
        f32x4 s0 = a0h + a0l, s1 = a1h + a1l, s2 = a2h + a2l;

        // G: lagged back-pressure (flag=t-1 was stored ~1.5 steps ago -> rarely waits).
        // flags >= t-1 certifies: partners done reading slot t&1's old content AND
        // partners' stores <= t-2 visible (ghost-kill for next step's staging).
        {
            const int want = t - 1;
            int guard2 = 0;
            for (;;) {
                int f = 0x7fffffff;
                if (lane < JBL)
                    f = __hip_atomic_load(fbase + lane, __ATOMIC_RELAXED,
                                          __HIP_MEMORY_SCOPE_AGENT);
                if (__all(f >= want)) break;
                __builtin_amdgcn_s_sleep(1);
                if (++guard2 > (1 << 17)) break;
            }
        }

        // H: epilogue + tagged stores (no drain!)  D layout: col=lane&15, row=lq*4+i
        const u32 tgs = (u32)(t & 3);
        u32* dst = (t & 1) ? hbuf1 : hbuf0;
        #pragma unroll
        for (int i = 0; i < 4; ++i) {
            int row = b0 + lq * 4 + i;
            float r = sigm(s0[i] + gr[i]);
            float z = sigm(s1[i] + gz[i]);
            float n = tanh_fast(gn[i] + r * (s2[i] + bhn));
            float hnew = (1.f - z) * n + z * hp[i];
            float hout = (t <= lv[i]) ? hnew : hp[i];
            hp[i] = hout;
            unsigned short hi = f2bf(hout);
            unsigned short lo = f2bf(hout - bf2f(hi));
            u32 pk = ((u32)hi << 16) | (u32)(lo & 0xFFFC) | tgs;
            __hip_atomic_store(dst + (size_t)row * HH + jc, pk,
                               __ATOMIC_RELAXED, __HIP_MEMORY_SCOPE_AGENT);
        }
        __syncthreads();                       // I: LDS reuse guard
    }
}

__global__ void k_logits(const u32* __restrict__ h_pk, const int* __restrict__ lastvalid,
                         const float* __restrict__ fc_w, const float* __restrict__ fc_b,
                         float* __restrict__ out) {
    int wave = threadIdx.x >> 6, lane = threadIdx.x & 63;
    int row = blockIdx.x * 4 + wave;
    if (row >= BB) return;
    int g0 = (row / BT) * BT;
    int gmax = 0;
    for (int r = 0; r < BT; ++r) gmax = max(gmax, lastvalid[g0 + r]);
    const u32* hf = h_pk + (size_t)(gmax & 1) * BB * HH + (size_t)row * HH;
    float d0 = 0.f, d1 = 0.f;
    int k = lane * 8;                          // 64 lanes x 8 = 512, single pass
    #pragma unroll
    for (int u = 0; u < 8; ++u) {
        u32 p = hf[k + u];
        float hv = bf2f((unsigned short)(p >> 16)) + bf2f((unsigned short)(p & 0xFFFC));
        d0 += hv * fc_w[k + u];
        d1 += hv * fc_w[HH + k + u];
    }
    #pragma unroll
    for (int off = 32; off; off >>= 1) {
        d0 += __shfl_xor(d0, off);
        d1 += __shfl_xor(d1, off);
    }
    if (lane == 0) {
        out[row * 2 + 0] = d0 + fc_b[0];
        out[row * 2 + 1] = d1 + fc_b[1];
    }
}

extern "C" void kernel_launch(void* const* d_in, const int* in_sizes, int n_in,
                              void* d_out, int out_size, void* d_ws, size_t ws_size,
                              hipStream_t stream) {
    const int*   x32   = (const int*)d_in[0];
    const float* embed = (const float*)d_in[1];
    const float* w_ih  = (const float*)d_in[2];
    const float* w_hh  = (const float*)d_in[3];
    const float* b_ih  = (const float*)d_in[4];
    const float* b_hh  = (const float*)d_in[5];
    const float* fc_w  = (const float*)d_in[6];
    const float* fc_b  = (const float*)d_in[7];
    float* out = (float*)d_out;

    char* ws = (char*)d_ws;
    unsigned short* wbf = (unsigned short*)ws;               // 1536*512*2 = 1572864 B
    u32* h_pk           = (u32*)(ws + 1572864);              // 2 slots * 512*512*4 = 2097152 B
    float* gi_table     = (float*)(ws + 3670016);            // 30*1536*4 = 184320 B
    int* lastvalid      = (int*)(ws + 3854336);              // 2048 B
    int* flags          = (int*)(ws + 3856384);              // 1024 B

    hipMemsetAsync(flags, 0, NBLK * sizeof(int), stream);
    k_wconv<<<(G3 * HH + 255) / 256, 256, 0, stream>>>(w_hh, wbf, G3 * HH);
    k_gitab<<<(NVOC * G3 + 255) / 256, 256, 0, stream>>>(embed, w_ih, b_ih, b_hh, gi_table);
    k_init<<<BB, 64, 0, stream>>>(x32, embed, h_pk, lastvalid);
    k_main<<<NBLK, 256, 0, stream>>>(x32, wbf, gi_table, b_hh, h_pk, lastvalid, flags);
    k_logits<<<BB / 4, 256, 0, stream>>>(h_pk, lastvalid, fc_w, fc_b, out);
}